// Round 3
// baseline (388.350 us; speedup 1.0000x reference)
//
#include <hip/hip_runtime.h>
#include <math.h>

// PlanarFlow: B=16384 rows, 32 steps, latent 64.
// 4 rows per wave, 16 lanes per row, one float4 of z per lane.
// All global loads are dwordx4; reductions are 16-lane pure-DPP butterflies
// (row_ror:8, row_ror:4, quad_perm xor2, quad_perm xor1) -> every lane holds
// the full sum, no broadcast needed on the critical chain.

constexpr int BATCH = 16384;
constexpr int STEPS = 32;
constexpr int LAT   = 64;
constexpr int IN_W  = STEPS * (2 * LAT + 1) + 2 * LAT;  // 4256

template <int CTRL>
__device__ __forceinline__ float dpp_mov(float x) {
    return __int_as_float(
        __builtin_amdgcn_update_dpp(0, __float_as_int(x), CTRL, 0xF, 0xF, true));
}

// Butterfly sum over each 16-lane row; ALL 16 lanes end with the full sum.
__device__ __forceinline__ float red16(float x) {
    x += dpp_mov<0x128>(x);  // row_ror:8
    x += dpp_mov<0x124>(x);  // row_ror:4
    x += dpp_mov<0x4E>(x);   // quad_perm [2,3,0,1] (xor 2)
    x += dpp_mov<0xB1>(x);   // quad_perm [1,0,3,2] (xor 1)
    return x;
}

__global__ __launch_bounds__(256)
void planar_flow_kernel(const float* __restrict__ inputs,
                        const float* __restrict__ noise,
                        float* __restrict__ z_out,
                        float* __restrict__ loss_out)
{
    const int lane  = threadIdx.x & 63;
    const int wv    = threadIdx.x >> 6;       // wave in block (0..3)
    const int group = lane >> 4;              // row-group within wave (0..3)
    const int li    = lane & 15;              // lane within row-group
    const int row   = blockIdx.x * 16 + wv * 4 + group;

    const float* rp = inputs + (size_t)row * IN_W;

    // ---- q0 / z0 / KL term (all dwordx4) ----
    float4 mu  = *(const float4*)(rp + 4 * li);             // [0,64)
    float4 ls2 = *(const float4*)(rp + LAT + 4 * li);       // [64,128)
    float4 nz  = *(const float4*)(noise + (size_t)row * LAT + 4 * li);

    float4 z;
    z.x = mu.x + nz.x * __expf(0.5f * ls2.x);
    z.y = mu.y + nz.y * __expf(0.5f * ls2.y);
    z.z = mu.z + nz.z * __expf(0.5f * ls2.z);
    z.w = mu.w + nz.w * __expf(0.5f * ls2.w);

    float klp = nz.x * nz.x + nz.y * nz.y + nz.z * nz.z + nz.w * nz.w
              + ls2.x + ls2.y + ls2.z + ls2.w;
    float acc = -0.5f * red16(klp);           // identical on all 16 lanes

    const float* up = rp + 2 * LAT;                    // U: [128, 2176)
    const float* wp = rp + 2 * LAT + STEPS * LAT;      // W: [2176, 4224)
    const float* bp = rp + 2 * LAT + 2 * STEPS * LAT;  // b: [4224, 4256)

    #pragma unroll 8
    for (int s = 0; s < STEPS; ++s) {
        float4 u = *(const float4*)(up + s * LAT + 4 * li);
        float4 w = *(const float4*)(wp + s * LAT + 4 * li);
        float bs = bp[s];                     // L1-hit broadcast load

        float wz = w.x * z.x + w.y * z.y + w.z * z.z + w.w * z.w;
        float uw = u.x * w.x + u.y * w.y + u.z * w.z + u.w * w.w;
        if (li == 0) wz += bs;                // fold b before the butterfly

        wz = red16(wz);                       // h on all 16 lanes
        uw = red16(uw);

        // tanh(h) = 1 - 2/(exp(2h)+1); saturates to +/-1 on overflow
        float e = __expf(2.0f * wz);
        float t = 1.0f - 2.0f * __builtin_amdgcn_rcpf(e + 1.0f);

        acc -= __logf(fabsf((1.0f - t * t) * uw + 1.0f));

        z.x += u.x * t; z.y += u.y * t; z.z += u.z * t; z.w += u.w * t;
    }

    // ---- write z (dwordx4, contiguous per group) ----
    *(float4*)(z_out + (size_t)row * LAT + 4 * li) = z;

    // ---- loss: one value per row-group -> LDS -> one atomic per block ----
    __shared__ float partial[16];
    if (li == 0) partial[wv * 4 + group] = acc;
    __syncthreads();
    if (threadIdx.x == 0) {
        float s = 0.0f;
        #pragma unroll
        for (int i = 0; i < 16; ++i) s += partial[i];
        atomicAdd(loss_out, s * (1.0f / BATCH));
    }
}

extern "C" void kernel_launch(void* const* d_in, const int* in_sizes, int n_in,
                              void* d_out, int out_size, void* d_ws, size_t ws_size,
                              hipStream_t stream)
{
    const float* inputs = (const float*)d_in[0];
    const float* noise  = (const float*)d_in[1];
    float* z_out    = (float*)d_out;
    float* loss_out = (float*)d_out + (size_t)BATCH * LAT;

    // d_out is poisoned 0xAA before every timed launch — zero the loss slot.
    hipMemsetAsync(loss_out, 0, sizeof(float), stream);

    planar_flow_kernel<<<dim3(BATCH / 16), dim3(256), 0, stream>>>(
        inputs, noise, z_out, loss_out);
}